// Round 2
// baseline (1503.001 us; speedup 1.0000x reference)
//
#include <hip/hip_runtime.h>
#include <hip/hip_bf16.h>

#define HD 64
#define N_AG 8
#define N_EN 8
#define N_AL 7
#define E_FEAT 9
#define A_FEAT 10
#define OWN_FEAT 16
#define N_ACT 14
#define EW2_COLS 641   // (E_FEAT+1)*HD + 1
#define AW2_COLS 640   // A_FEAT*HD

__global__ __launch_bounds__(64) void agent_kernel(
    const float* __restrict__ own_feats,    // [R,16]
    const float* __restrict__ enemy_feats,  // [R*8,9]
    const float* __restrict__ ally_feats,   // [R*7,10]
    const float* __restrict__ hidden_state, // [R,64]
    const int*  __restrict__ agent_idx,     // [R]
    const int*  __restrict__ last_act_idx,  // [R]
    const float* __restrict__ fc1_own_w, const float* __restrict__ fc1_own_b,
    const float* __restrict__ agent_id_emb, const float* __restrict__ action_id_emb,
    const float* __restrict__ he_w1, const float* __restrict__ he_b1,
    const float* __restrict__ he_w2, const float* __restrict__ he_b2,
    const float* __restrict__ ha_w1, const float* __restrict__ ha_b1,
    const float* __restrict__ ha_w2, const float* __restrict__ ha_b2,
    const float* __restrict__ gru_w_ih, const float* __restrict__ gru_w_hh,
    const float* __restrict__ gru_b_ih, const float* __restrict__ gru_b_hh,
    const float* __restrict__ fc2_w, const float* __restrict__ fc2_b,
    float* __restrict__ out_q,   // [R,14]
    float* __restrict__ out_hh)  // [R,64]
{
    const int n = blockIdx.x;
    const int tid = threadIdx.x;  // 0..63, one wave per block

    __shared__ float s_feat[16];
    __shared__ float s_P[64][10];
    __shared__ float s_x[64];
    __shared__ float s_h[64];
    __shared__ float s_hh[64];

    // ---------------- own embedding ----------------
    if (tid < OWN_FEAT) s_feat[tid] = own_feats[(size_t)n * OWN_FEAT + tid];
    __syncthreads();
    float emb = fc1_own_b[tid];
    #pragma unroll
    for (int f = 0; f < OWN_FEAT; ++f)
        emb += s_feat[f] * fc1_own_w[f * HD + tid];
    {
        const int ai = agent_idx[n];
        const int la = last_act_idx[n];
        emb += agent_id_emb[ai * HD + tid] + action_id_emb[la * HD + tid];
    }
    __syncthreads();

    // ---------------- enemies: L1 + P accumulation ----------------
    float re[N_EN];           // r component (k = tid) for each enemy; kept for attack head
    float Pe[E_FEAT];         // P[tid][f] = sum_e r_e[tid] * ef[e][f]
    float seF[E_FEAT];        // sum_e ef[e][f]
    #pragma unroll
    for (int f = 0; f < E_FEAT; ++f) { Pe[f] = 0.f; seF[f] = 0.f; }

    for (int e = 0; e < N_EN; ++e) {
        if (tid < E_FEAT) s_feat[tid] = enemy_feats[((size_t)n * N_EN + e) * E_FEAT + tid];
        __syncthreads();
        float ef[E_FEAT];
        #pragma unroll
        for (int f = 0; f < E_FEAT; ++f) ef[f] = s_feat[f];
        float acc = he_b1[tid];
        #pragma unroll
        for (int f = 0; f < E_FEAT; ++f) acc += ef[f] * he_w1[f * HD + tid];
        float r = fmaxf(acc, 0.f);
        re[e] = r;
        #pragma unroll
        for (int f = 0; f < E_FEAT; ++f) { Pe[f] += r * ef[f]; seF[f] += ef[f]; }
        __syncthreads();
    }
    #pragma unroll
    for (int f = 0; f < E_FEAT; ++f) s_P[tid][f] = Pe[f];
    __syncthreads();
    // contraction: emb_en[tid] = sum_f seF[f]*b2[f*64+tid] + sum_{k,f} P[k][f]*W2[k, f*64+tid]
    {
        float acc = 0.f;
        #pragma unroll
        for (int f = 0; f < E_FEAT; ++f) acc += seF[f] * he_b2[f * HD + tid];
        for (int k = 0; k < HD; ++k) {
            const float* w2row = he_w2 + (size_t)k * EW2_COLS + tid;
            #pragma unroll
            for (int f = 0; f < E_FEAT; ++f)
                acc += s_P[k][f] * w2row[f * HD];
        }
        emb += acc;
    }
    __syncthreads();

    // ---------------- allies: L1 + P accumulation ----------------
    float Pa[A_FEAT];
    float saF[A_FEAT];
    #pragma unroll
    for (int f = 0; f < A_FEAT; ++f) { Pa[f] = 0.f; saF[f] = 0.f; }

    for (int a = 0; a < N_AL; ++a) {
        if (tid < A_FEAT) s_feat[tid] = ally_feats[((size_t)n * N_AL + a) * A_FEAT + tid];
        __syncthreads();
        float af[A_FEAT];
        #pragma unroll
        for (int f = 0; f < A_FEAT; ++f) af[f] = s_feat[f];
        float acc = ha_b1[tid];
        #pragma unroll
        for (int f = 0; f < A_FEAT; ++f) acc += af[f] * ha_w1[f * HD + tid];
        float r = fmaxf(acc, 0.f);
        #pragma unroll
        for (int f = 0; f < A_FEAT; ++f) { Pa[f] += r * af[f]; saF[f] += af[f]; }
        __syncthreads();
    }
    #pragma unroll
    for (int f = 0; f < A_FEAT; ++f) s_P[tid][f] = Pa[f];
    __syncthreads();
    {
        float acc = 0.f;
        #pragma unroll
        for (int f = 0; f < A_FEAT; ++f) acc += saF[f] * ha_b2[f * HD + tid];
        for (int k = 0; k < HD; ++k) {
            const float* w2row = ha_w2 + (size_t)k * AW2_COLS + tid;
            #pragma unroll
            for (int f = 0; f < A_FEAT; ++f)
                acc += s_P[k][f] * w2row[f * HD];
        }
        emb += acc;
    }

    // ---------------- x, GRU ----------------
    float x = fmaxf(emb, 0.f);
    s_x[tid] = x;
    s_h[tid] = hidden_state[(size_t)n * HD + tid];
    __syncthreads();

    float gi_r = gru_b_ih[tid];
    float gi_z = gru_b_ih[HD + tid];
    float gi_n = gru_b_ih[2 * HD + tid];
    float gh_r = gru_b_hh[tid];
    float gh_z = gru_b_hh[HD + tid];
    float gh_n = gru_b_hh[2 * HD + tid];
    {
        const float* wih_r = gru_w_ih + (size_t)tid * HD;
        const float* wih_z = gru_w_ih + (size_t)(HD + tid) * HD;
        const float* wih_n = gru_w_ih + (size_t)(2 * HD + tid) * HD;
        const float* whh_r = gru_w_hh + (size_t)tid * HD;
        const float* whh_z = gru_w_hh + (size_t)(HD + tid) * HD;
        const float* whh_n = gru_w_hh + (size_t)(2 * HD + tid) * HD;
        for (int k = 0; k < HD; ++k) {
            float xk = s_x[k], hk = s_h[k];
            gi_r += xk * wih_r[k];
            gi_z += xk * wih_z[k];
            gi_n += xk * wih_n[k];
            gh_r += hk * whh_r[k];
            gh_z += hk * whh_z[k];
            gh_n += hk * whh_n[k];
        }
    }
    float rg = 1.f / (1.f + __expf(-(gi_r + gh_r)));
    float zg = 1.f / (1.f + __expf(-(gi_z + gh_z)));
    float ng = tanhf(gi_n + rg * gh_n);
    float hv = (1.f - zg) * ng + zg * s_h[tid];
    s_hh[tid] = hv;
    out_hh[(size_t)n * HD + tid] = hv;
    __syncthreads();

    // ---------------- q_normal (6 outputs) ----------------
    if (tid < 6) {
        float q = fc2_b[tid];
        for (int k = 0; k < HD; ++k) q += s_hh[k] * fc2_w[k * 6 + tid];
        out_q[(size_t)n * N_ACT + tid] = q;
    }

    // ---------------- q_attack (8 outputs) ----------------
    // u[k=tid] = sum_h hh[h]*W2[k,576+h] + W2[k,640]
    {
        const float* w2t = he_w2 + (size_t)tid * EW2_COLS + (E_FEAT * HD);  // col 576
        float u = w2t[HD];  // col 640
        for (int h = 0; h < HD; ++h) u += s_hh[h] * w2t[h];
        // c = sum_h hh[h]*b2[576+h] + b2[640]
        float c = s_hh[tid] * he_b2[E_FEAT * HD + tid];
        #pragma unroll
        for (int o = 1; o < 64; o <<= 1) c += __shfl_xor(c, o);
        c += he_b2[E_FEAT * HD + HD];
        #pragma unroll
        for (int e = 0; e < N_EN; ++e) {
            float p = re[e] * u;
            #pragma unroll
            for (int o = 1; o < 64; o <<= 1) p += __shfl_xor(p, o);
            if (tid == e) out_q[(size_t)n * N_ACT + 6 + e] = p + c;
        }
    }
}

extern "C" void kernel_launch(void* const* d_in, const int* in_sizes, int n_in,
                              void* d_out, int out_size, void* d_ws, size_t ws_size,
                              hipStream_t stream) {
    const float* own_feats    = (const float*)d_in[0];
    const float* enemy_feats  = (const float*)d_in[1];
    const float* ally_feats   = (const float*)d_in[2];
    const float* hidden_state = (const float*)d_in[3];
    const int*  agent_idx     = (const int*)d_in[4];
    const int*  last_act      = (const int*)d_in[5];
    // d_in[6] = bs (scalar), unused: derive R from sizes
    const float* fc1_own_w = (const float*)d_in[7];
    const float* fc1_own_b = (const float*)d_in[8];
    const float* agent_id_emb  = (const float*)d_in[9];
    const float* action_id_emb = (const float*)d_in[10];
    const float* he_w1 = (const float*)d_in[11];
    const float* he_b1 = (const float*)d_in[12];
    const float* he_w2 = (const float*)d_in[13];
    const float* he_b2 = (const float*)d_in[14];
    const float* ha_w1 = (const float*)d_in[15];
    const float* ha_b1 = (const float*)d_in[16];
    const float* ha_w2 = (const float*)d_in[17];
    const float* ha_b2 = (const float*)d_in[18];
    const float* gru_w_ih = (const float*)d_in[19];
    const float* gru_w_hh = (const float*)d_in[20];
    const float* gru_b_ih = (const float*)d_in[21];
    const float* gru_b_hh = (const float*)d_in[22];
    const float* fc2_w = (const float*)d_in[23];
    const float* fc2_b = (const float*)d_in[24];

    const int R = in_sizes[0] / OWN_FEAT;  // bs * N_AG = 32768
    float* out_q  = (float*)d_out;
    float* out_hh = out_q + (size_t)R * N_ACT;

    agent_kernel<<<R, 64, 0, stream>>>(
        own_feats, enemy_feats, ally_feats, hidden_state, agent_idx, last_act,
        fc1_own_w, fc1_own_b, agent_id_emb, action_id_emb,
        he_w1, he_b1, he_w2, he_b2, ha_w1, ha_b1, ha_w2, ha_b2,
        gru_w_ih, gru_w_hh, gru_b_ih, gru_b_hh, fc2_w, fc2_b,
        out_q, out_hh);
}

// Round 3
// 395.103 us; speedup vs baseline: 3.8041x; 3.8041x over previous
//
#include <hip/hip_runtime.h>

#define HD 64
#define N_EN 8
#define N_AL 7
#define E_FEAT 9
#define A_FEAT 10
#define OWN_FEAT 16
#define N_ACT 14
#define EW2 641
#define AW2 640
#define NR 4
#define NWAVE 4
#define ROWS_PER_BLOCK (NR * NWAVE)

// ws layout (floats)
#define WS_WTIH 0          // [64][192] : WT_ih[k][j] = gru_w_ih[j][k]
#define WS_WTHH 12288      // [64][192]
#define WS_AT   24576      // [64][64]  : AT[h][k] = he_w2[k][576+h]
#define WS_UB   28672      // [64]      : ub[k] = he_w2[k][640]
#define WS_TOTAL 28736

__global__ __launch_bounds__(256) void prep_kernel(
    const float* __restrict__ gru_w_ih, const float* __restrict__ gru_w_hh,
    const float* __restrict__ he_w2, float* __restrict__ ws)
{
    int idx = blockIdx.x * 256 + threadIdx.x;
    if (idx < 12288) {
        int k = idx / 192, j = idx % 192;
        ws[WS_WTIH + idx] = gru_w_ih[j * HD + k];
    } else if (idx < 24576) {
        int t = idx - 12288; int k = t / 192, j = t % 192;
        ws[idx] = gru_w_hh[j * HD + k];
    } else if (idx < 28672) {
        int t = idx - 24576; int h = t >> 6, k = t & 63;
        ws[idx] = he_w2[k * EW2 + E_FEAT * HD + h];
    } else if (idx < WS_TOTAL) {
        int k = idx - 28672;
        ws[idx] = he_w2[k * EW2 + 640];
    }
}

__device__ __forceinline__ float wave_sum(float v) {
    #pragma unroll
    for (int o = 1; o < 64; o <<= 1) v += __shfl_xor(v, o);
    return v;
}
__device__ __forceinline__ float sigm(float x) { return 1.f / (1.f + __expf(-x)); }

// Per-wave LDS slice: 2560 floats.
//   P phase : Pmain[r][k][8]  at r*512 + k*8        (0..2047)
//             Ptail[r][k][2]  at 2048 + r*128 + k*2 (2048..2559)
//   GRU/out : xh[k][r][2]     at k*8 + r*2          (0..511)   (P dead by then)
//             hh[h][r]        at 512 + h*4 + r      (512..767)
__global__ __launch_bounds__(256, 4) void agent_kernel(
    const float* __restrict__ own_feats,
    const float* __restrict__ enemy_feats,
    const float* __restrict__ ally_feats,
    const float* __restrict__ hidden_state,
    const int*  __restrict__ agent_idx,
    const int*  __restrict__ last_act_idx,
    const float* __restrict__ fc1_own_w, const float* __restrict__ fc1_own_b,
    const float* __restrict__ agent_id_emb, const float* __restrict__ action_id_emb,
    const float* __restrict__ he_w1, const float* __restrict__ he_b1,
    const float* __restrict__ he_w2, const float* __restrict__ he_b2,
    const float* __restrict__ ha_w1, const float* __restrict__ ha_b1,
    const float* __restrict__ ha_w2, const float* __restrict__ ha_b2,
    const float* __restrict__ gru_b_ih, const float* __restrict__ gru_b_hh,
    const float* __restrict__ fc2_w, const float* __restrict__ fc2_b,
    const float* __restrict__ ws,
    float* __restrict__ out_q, float* __restrict__ out_hh)
{
    __shared__ __align__(16) float smem[NWAVE * 2560];
    const int lane = threadIdx.x & 63;
    const int wv   = threadIdx.x >> 6;
    float* W = smem + wv * 2560;
    const int n0 = blockIdx.x * ROWS_PER_BLOCK + wv * NR;

    // ---------------- OWN ----------------
    float wown[OWN_FEAT];
    #pragma unroll
    for (int f = 0; f < OWN_FEAT; ++f) wown[f] = fc1_own_w[f * HD + lane];
    const float bown = fc1_own_b[lane];
    float emb[NR];
    #pragma unroll
    for (int r = 0; r < NR; ++r) {
        const int n = n0 + r;
        const int ai = agent_idx[n], la = last_act_idx[n];
        float e = bown + agent_id_emb[ai * HD + lane] + action_id_emb[la * HD + lane];
        const float* of = own_feats + (size_t)n * OWN_FEAT;
        #pragma unroll
        for (int f = 0; f < OWN_FEAT; ++f) e += of[f] * wown[f];
        emb[r] = e;
    }

    float re[NR][N_EN];

    // ---------------- ENEMY: L1 + P build ----------------
    {
        float w1[E_FEAT], b2v[E_FEAT];
        #pragma unroll
        for (int f = 0; f < E_FEAT; ++f) {
            w1[f]  = he_w1[f * HD + lane];
            b2v[f] = he_b2[f * HD + lane];
        }
        const float b1 = he_b1[lane];
        #pragma unroll
        for (int r = 0; r < NR; ++r) {
            const int n = n0 + r;
            float pf[E_FEAT];
            #pragma unroll
            for (int f = 0; f < E_FEAT; ++f) pf[f] = 0.f;
            const float* efb = enemy_feats + (size_t)n * (N_EN * E_FEAT);
            #pragma unroll
            for (int e = 0; e < N_EN; ++e) {
                float ef[E_FEAT];
                #pragma unroll
                for (int f = 0; f < E_FEAT; ++f) ef[f] = efb[e * E_FEAT + f];
                float acc = b1;
                #pragma unroll
                for (int f = 0; f < E_FEAT; ++f) acc += ef[f] * w1[f];
                const float rr = fmaxf(acc, 0.f);
                re[r][e] = rr;
                #pragma unroll
                for (int f = 0; f < E_FEAT; ++f) pf[f] += rr * ef[f];
                #pragma unroll
                for (int f = 0; f < E_FEAT; ++f) emb[r] += ef[f] * b2v[f];
            }
            float* pm = W + r * 512 + lane * 8;
            float4 a = make_float4(pf[0], pf[1], pf[2], pf[3]);
            float4 b = make_float4(pf[4], pf[5], pf[6], pf[7]);
            *reinterpret_cast<float4*>(pm)     = a;
            *reinterpret_cast<float4*>(pm + 4) = b;
            W[2048 + r * 128 + lane * 2] = pf[8];
        }
    }
    __builtin_amdgcn_wave_barrier();

    // ---------------- w2_e contraction ----------------
    #pragma unroll 2
    for (int k = 0; k < HD; ++k) {
        const float* wrow = he_w2 + (size_t)k * EW2 + lane;
        float w9[E_FEAT];
        #pragma unroll
        for (int f = 0; f < E_FEAT; ++f) w9[f] = wrow[f * HD];
        #pragma unroll
        for (int r = 0; r < NR; ++r) {
            const float4 p0 = *reinterpret_cast<const float4*>(W + r * 512 + k * 8);
            const float4 p1 = *reinterpret_cast<const float4*>(W + r * 512 + k * 8 + 4);
            const float p8 = W[2048 + r * 128 + k * 2];
            float a = emb[r];
            a += p0.x * w9[0]; a += p0.y * w9[1]; a += p0.z * w9[2]; a += p0.w * w9[3];
            a += p1.x * w9[4]; a += p1.y * w9[5]; a += p1.z * w9[6]; a += p1.w * w9[7];
            a += p8 * w9[8];
            emb[r] = a;
        }
    }
    __builtin_amdgcn_wave_barrier();

    // ---------------- ALLY: L1 + P build ----------------
    {
        float w1[A_FEAT], b2v[A_FEAT];
        #pragma unroll
        for (int f = 0; f < A_FEAT; ++f) {
            w1[f]  = ha_w1[f * HD + lane];
            b2v[f] = ha_b2[f * HD + lane];
        }
        const float b1 = ha_b1[lane];
        #pragma unroll
        for (int r = 0; r < NR; ++r) {
            const int n = n0 + r;
            float pf[A_FEAT];
            #pragma unroll
            for (int f = 0; f < A_FEAT; ++f) pf[f] = 0.f;
            const float* afb = ally_feats + (size_t)n * (N_AL * A_FEAT);
            #pragma unroll
            for (int e = 0; e < N_AL; ++e) {
                float af[A_FEAT];
                #pragma unroll
                for (int f = 0; f < A_FEAT; ++f) af[f] = afb[e * A_FEAT + f];
                float acc = b1;
                #pragma unroll
                for (int f = 0; f < A_FEAT; ++f) acc += af[f] * w1[f];
                const float rr = fmaxf(acc, 0.f);
                #pragma unroll
                for (int f = 0; f < A_FEAT; ++f) pf[f] += rr * af[f];
                #pragma unroll
                for (int f = 0; f < A_FEAT; ++f) emb[r] += af[f] * b2v[f];
            }
            float* pm = W + r * 512 + lane * 8;
            float4 a = make_float4(pf[0], pf[1], pf[2], pf[3]);
            float4 b = make_float4(pf[4], pf[5], pf[6], pf[7]);
            *reinterpret_cast<float4*>(pm)     = a;
            *reinterpret_cast<float4*>(pm + 4) = b;
            float* pt = W + 2048 + r * 128 + lane * 2;
            pt[0] = pf[8]; pt[1] = pf[9];
        }
    }
    __builtin_amdgcn_wave_barrier();

    // ---------------- w2_a contraction ----------------
    #pragma unroll 2
    for (int k = 0; k < HD; ++k) {
        const float* wrow = ha_w2 + (size_t)k * AW2 + lane;
        float w10[A_FEAT];
        #pragma unroll
        for (int f = 0; f < A_FEAT; ++f) w10[f] = wrow[f * HD];
        #pragma unroll
        for (int r = 0; r < NR; ++r) {
            const float4 p0 = *reinterpret_cast<const float4*>(W + r * 512 + k * 8);
            const float4 p1 = *reinterpret_cast<const float4*>(W + r * 512 + k * 8 + 4);
            const float2 pt = *reinterpret_cast<const float2*>(W + 2048 + r * 128 + k * 2);
            float a = emb[r];
            a += p0.x * w10[0]; a += p0.y * w10[1]; a += p0.z * w10[2]; a += p0.w * w10[3];
            a += p1.x * w10[4]; a += p1.y * w10[5]; a += p1.z * w10[6]; a += p1.w * w10[7];
            a += pt.x * w10[8]; a += pt.y * w10[9];
            emb[r] = a;
        }
    }
    __builtin_amdgcn_wave_barrier();

    // ---------------- GRU ----------------
    float hreg[NR], hv[NR];
    #pragma unroll
    for (int r = 0; r < NR; ++r) {
        const int n = n0 + r;
        const float x = fmaxf(emb[r], 0.f);
        const float h = hidden_state[(size_t)n * HD + lane];
        hreg[r] = h;
        W[lane * 8 + r * 2]     = x;
        W[lane * 8 + r * 2 + 1] = h;
    }
    __builtin_amdgcn_wave_barrier();

    {
        float gir[NR], giz[NR], gin[NR], ghr[NR], ghz[NR], ghn[NR];
        const float bir = gru_b_ih[lane], biz = gru_b_ih[HD + lane], bin = gru_b_ih[2 * HD + lane];
        const float bhr = gru_b_hh[lane], bhz = gru_b_hh[HD + lane], bhn = gru_b_hh[2 * HD + lane];
        #pragma unroll
        for (int r = 0; r < NR; ++r) {
            gir[r] = bir; giz[r] = biz; gin[r] = bin;
            ghr[r] = bhr; ghz[r] = bhz; ghn[r] = bhn;
        }
        const float* wtih = ws + WS_WTIH;
        const float* wthh = ws + WS_WTHH;
        #pragma unroll 2
        for (int k = 0; k < HD; ++k) {
            const float wi0 = wtih[k * 192 + lane];
            const float wi1 = wtih[k * 192 + HD + lane];
            const float wi2 = wtih[k * 192 + 2 * HD + lane];
            const float wh0 = wthh[k * 192 + lane];
            const float wh1 = wthh[k * 192 + HD + lane];
            const float wh2 = wthh[k * 192 + 2 * HD + lane];
            #pragma unroll
            for (int r = 0; r < NR; ++r) {
                const float2 xh = *reinterpret_cast<const float2*>(W + k * 8 + r * 2);
                gir[r] += xh.x * wi0; giz[r] += xh.x * wi1; gin[r] += xh.x * wi2;
                ghr[r] += xh.y * wh0; ghz[r] += xh.y * wh1; ghn[r] += xh.y * wh2;
            }
        }
        #pragma unroll
        for (int r = 0; r < NR; ++r) {
            const int n = n0 + r;
            const float rg = sigm(gir[r] + ghr[r]);
            const float zg = sigm(giz[r] + ghz[r]);
            const float ng = tanhf(gin[r] + rg * ghn[r]);
            const float h = (1.f - zg) * ng + zg * hreg[r];
            hv[r] = h;
            out_hh[(size_t)n * HD + lane] = h;
            W[512 + lane * 4 + r] = h;
        }
    }
    __builtin_amdgcn_wave_barrier();

    // ---------------- q_normal ----------------
    {
        float w6[6];
        #pragma unroll
        for (int j = 0; j < 6; ++j) w6[j] = fc2_w[lane * 6 + j];
        #pragma unroll
        for (int r = 0; r < NR; ++r) {
            const int n = n0 + r;
            float pj[6];
            #pragma unroll
            for (int j = 0; j < 6; ++j) pj[j] = hv[r] * w6[j];
            #pragma unroll
            for (int o = 1; o < 64; o <<= 1) {
                #pragma unroll
                for (int j = 0; j < 6; ++j) pj[j] += __shfl_xor(pj[j], o);
            }
            if (lane < 6) {
                const float q = (lane == 0) ? pj[0] : (lane == 1) ? pj[1] : (lane == 2) ? pj[2]
                              : (lane == 3) ? pj[3] : (lane == 4) ? pj[4] : pj[5];
                out_q[(size_t)n * N_ACT + lane] = q + fc2_b[lane];
            }
        }
    }

    // ---------------- attack head ----------------
    {
        const float* AT = ws + WS_AT;
        const float* ubp = ws + WS_UB;
        float u[NR];
        const float ubv = ubp[lane];
        #pragma unroll
        for (int r = 0; r < NR; ++r) u[r] = ubv;
        #pragma unroll 4
        for (int h = 0; h < HD; ++h) {
            const float at = AT[h * HD + lane];
            const float4 h4 = *reinterpret_cast<const float4*>(W + 512 + h * 4);
            u[0] += h4.x * at; u[1] += h4.y * at; u[2] += h4.z * at; u[3] += h4.w * at;
        }
        const float b2a = he_b2[E_FEAT * HD + lane];
        const float b2last = he_b2[E_FEAT * HD + HD];
        #pragma unroll
        for (int r = 0; r < NR; ++r) {
            const int n = n0 + r;
            const float c = wave_sum(hv[r] * b2a) + b2last;
            #pragma unroll
            for (int e = 0; e < N_EN; ++e) {
                const float p = wave_sum(re[r][e] * u[r]);
                if (lane == e) out_q[(size_t)n * N_ACT + 6 + e] = p + c;
            }
        }
    }
}

extern "C" void kernel_launch(void* const* d_in, const int* in_sizes, int n_in,
                              void* d_out, int out_size, void* d_ws, size_t ws_size,
                              hipStream_t stream) {
    const float* own_feats    = (const float*)d_in[0];
    const float* enemy_feats  = (const float*)d_in[1];
    const float* ally_feats   = (const float*)d_in[2];
    const float* hidden_state = (const float*)d_in[3];
    const int*  agent_idx     = (const int*)d_in[4];
    const int*  last_act      = (const int*)d_in[5];
    const float* fc1_own_w = (const float*)d_in[7];
    const float* fc1_own_b = (const float*)d_in[8];
    const float* agent_id_emb  = (const float*)d_in[9];
    const float* action_id_emb = (const float*)d_in[10];
    const float* he_w1 = (const float*)d_in[11];
    const float* he_b1 = (const float*)d_in[12];
    const float* he_w2 = (const float*)d_in[13];
    const float* he_b2 = (const float*)d_in[14];
    const float* ha_w1 = (const float*)d_in[15];
    const float* ha_b1 = (const float*)d_in[16];
    const float* ha_w2 = (const float*)d_in[17];
    const float* ha_b2 = (const float*)d_in[18];
    const float* gru_w_ih = (const float*)d_in[19];
    const float* gru_w_hh = (const float*)d_in[20];
    const float* gru_b_ih = (const float*)d_in[21];
    const float* gru_b_hh = (const float*)d_in[22];
    const float* fc2_w = (const float*)d_in[23];
    const float* fc2_b = (const float*)d_in[24];

    const int R = in_sizes[0] / OWN_FEAT;  // 32768
    float* ws = (float*)d_ws;
    float* out_q  = (float*)d_out;
    float* out_hh = out_q + (size_t)R * N_ACT;

    prep_kernel<<<(WS_TOTAL + 255) / 256, 256, 0, stream>>>(gru_w_ih, gru_w_hh, he_w2, ws);

    const int nblocks = R / ROWS_PER_BLOCK;
    agent_kernel<<<nblocks, NWAVE * 64, 0, stream>>>(
        own_feats, enemy_feats, ally_feats, hidden_state, agent_idx, last_act,
        fc1_own_w, fc1_own_b, agent_id_emb, action_id_emb,
        he_w1, he_b1, he_w2, he_b2, ha_w1, ha_b1, ha_w2, ha_b2,
        gru_b_ih, gru_b_hh, fc2_w, fc2_b, ws,
        out_q, out_hh);
}

// Round 4
// 282.520 us; speedup vs baseline: 5.3200x; 1.3985x over previous
//
#include <hip/hip_runtime.h>

#define HD 64
#define N_EN 8
#define N_AL 7
#define E_FEAT 9
#define A_FEAT 10
#define OWN_FEAT 16
#define N_ACT 14
#define EW2 641
#define AW2 640
#define NR 4
#define NWAVE 4
#define ROWS_PER_BLOCK (NR * NWAVE)

// ws layout (floats)
#define WS_WTIH 0          // [64][192] : WT_ih[k][j] = gru_w_ih[j][k]
#define WS_WTHH 12288      // [64][192]
#define WS_AT   24576      // [64][64]  : AT[h][k] = he_w2[k][576+h]
#define WS_UB   28672      // [64]      : ub[k] = he_w2[k][640]
#define WS_TOTAL 28736

__global__ __launch_bounds__(256) void prep_kernel(
    const float* __restrict__ gru_w_ih, const float* __restrict__ gru_w_hh,
    const float* __restrict__ he_w2, float* __restrict__ ws)
{
    int idx = blockIdx.x * 256 + threadIdx.x;
    if (idx < 12288) {
        int k = idx / 192, j = idx % 192;
        ws[WS_WTIH + idx] = gru_w_ih[j * HD + k];
    } else if (idx < 24576) {
        int t = idx - 12288; int k = t / 192, j = t % 192;
        ws[idx] = gru_w_hh[j * HD + k];
    } else if (idx < 28672) {
        int t = idx - 24576; int h = t >> 6, k = t & 63;
        ws[idx] = he_w2[k * EW2 + E_FEAT * HD + h];
    } else if (idx < WS_TOTAL) {
        int k = idx - 28672;
        ws[idx] = he_w2[k * EW2 + 640];
    }
}

__device__ __forceinline__ float wave_sum(float v) {
    #pragma unroll
    for (int o = 1; o < 64; o <<= 1) v += __shfl_xor(v, o);
    return v;
}
__device__ __forceinline__ float sigm(float x) { return 1.f / (1.f + __expf(-x)); }

// Per-wave LDS slice: 2560 floats.
//   P phase : Pmain[r][k][8]  at r*512 + k*8        (0..2047)
//             Ptail[r][k][2]  at 2048 + r*128 + k*2 (2048..2559)
//   GRU/out : xh[k][r][2]     at k*8 + r*2          (0..511)   (P dead by then)
//             hh[h][r]        at 512 + h*4 + r      (512..767)
__global__ __launch_bounds__(256, 2) void agent_kernel(
    const float* __restrict__ own_feats,
    const float* __restrict__ enemy_feats,
    const float* __restrict__ ally_feats,
    const float* __restrict__ hidden_state,
    const int*  __restrict__ agent_idx,
    const int*  __restrict__ last_act_idx,
    const float* __restrict__ fc1_own_w, const float* __restrict__ fc1_own_b,
    const float* __restrict__ agent_id_emb, const float* __restrict__ action_id_emb,
    const float* __restrict__ he_w1, const float* __restrict__ he_b1,
    const float* __restrict__ he_w2, const float* __restrict__ he_b2,
    const float* __restrict__ ha_w1, const float* __restrict__ ha_b1,
    const float* __restrict__ ha_w2, const float* __restrict__ ha_b2,
    const float* __restrict__ gru_b_ih, const float* __restrict__ gru_b_hh,
    const float* __restrict__ fc2_w, const float* __restrict__ fc2_b,
    const float* __restrict__ ws,
    float* __restrict__ out_q, float* __restrict__ out_hh)
{
    __shared__ __align__(16) float smem[NWAVE * 2560];
    const int lane = threadIdx.x & 63;
    const int wv   = threadIdx.x >> 6;
    float* W = smem + wv * 2560;
    const int n0 = blockIdx.x * ROWS_PER_BLOCK + wv * NR;

    // ---------------- OWN ----------------
    float emb[NR];
    {
        float wown[OWN_FEAT];
        #pragma unroll
        for (int f = 0; f < OWN_FEAT; ++f) wown[f] = fc1_own_w[f * HD + lane];
        const float bown = fc1_own_b[lane];
        #pragma unroll
        for (int r = 0; r < NR; ++r) {
            const int n = n0 + r;
            const int ai = agent_idx[n], la = last_act_idx[n];
            float e = bown + agent_id_emb[ai * HD + lane] + action_id_emb[la * HD + lane];
            const float* of = own_feats + (size_t)n * OWN_FEAT;
            #pragma unroll
            for (int f = 0; f < OWN_FEAT; ++f) e += of[f] * wown[f];
            emb[r] = e;
        }
    }

    // ---------------- ENEMY: L1 + P build (r values NOT kept; recomputed in attack) ----------------
    {
        float w1[E_FEAT], b2v[E_FEAT];
        #pragma unroll
        for (int f = 0; f < E_FEAT; ++f) {
            w1[f]  = he_w1[f * HD + lane];
            b2v[f] = he_b2[f * HD + lane];
        }
        const float b1 = he_b1[lane];
        #pragma unroll
        for (int r = 0; r < NR; ++r) {
            const int n = n0 + r;
            float pf[E_FEAT];
            #pragma unroll
            for (int f = 0; f < E_FEAT; ++f) pf[f] = 0.f;
            const float* efb = enemy_feats + (size_t)n * (N_EN * E_FEAT);
            float e_acc = 0.f;
            for (int e = 0; e < N_EN; ++e) {
                float ef[E_FEAT];
                #pragma unroll
                for (int f = 0; f < E_FEAT; ++f) ef[f] = efb[e * E_FEAT + f];
                float acc = b1;
                #pragma unroll
                for (int f = 0; f < E_FEAT; ++f) acc += ef[f] * w1[f];
                const float rr = fmaxf(acc, 0.f);
                #pragma unroll
                for (int f = 0; f < E_FEAT; ++f) pf[f] += rr * ef[f];
                #pragma unroll
                for (int f = 0; f < E_FEAT; ++f) e_acc += ef[f] * b2v[f];
            }
            emb[r] += e_acc;
            float* pm = W + r * 512 + lane * 8;
            *reinterpret_cast<float4*>(pm)     = make_float4(pf[0], pf[1], pf[2], pf[3]);
            *reinterpret_cast<float4*>(pm + 4) = make_float4(pf[4], pf[5], pf[6], pf[7]);
            W[2048 + r * 128 + lane * 2] = pf[8];
        }
    }
    __builtin_amdgcn_wave_barrier();

    // ---------------- w2_e contraction ----------------
    #pragma unroll 2
    for (int k = 0; k < HD; ++k) {
        const float* wrow = he_w2 + (size_t)k * EW2 + lane;
        float w9[E_FEAT];
        #pragma unroll
        for (int f = 0; f < E_FEAT; ++f) w9[f] = wrow[f * HD];
        #pragma unroll
        for (int r = 0; r < NR; ++r) {
            const float4 p0 = *reinterpret_cast<const float4*>(W + r * 512 + k * 8);
            const float4 p1 = *reinterpret_cast<const float4*>(W + r * 512 + k * 8 + 4);
            const float p8 = W[2048 + r * 128 + k * 2];
            float a = emb[r];
            a += p0.x * w9[0]; a += p0.y * w9[1]; a += p0.z * w9[2]; a += p0.w * w9[3];
            a += p1.x * w9[4]; a += p1.y * w9[5]; a += p1.z * w9[6]; a += p1.w * w9[7];
            a += p8 * w9[8];
            emb[r] = a;
        }
    }
    __builtin_amdgcn_wave_barrier();

    // ---------------- ALLY: L1 + P build ----------------
    {
        float w1[A_FEAT], b2v[A_FEAT];
        #pragma unroll
        for (int f = 0; f < A_FEAT; ++f) {
            w1[f]  = ha_w1[f * HD + lane];
            b2v[f] = ha_b2[f * HD + lane];
        }
        const float b1 = ha_b1[lane];
        #pragma unroll
        for (int r = 0; r < NR; ++r) {
            const int n = n0 + r;
            float pf[A_FEAT];
            #pragma unroll
            for (int f = 0; f < A_FEAT; ++f) pf[f] = 0.f;
            const float* afb = ally_feats + (size_t)n * (N_AL * A_FEAT);
            float a_acc = 0.f;
            for (int e = 0; e < N_AL; ++e) {
                float af[A_FEAT];
                #pragma unroll
                for (int f = 0; f < A_FEAT; ++f) af[f] = afb[e * A_FEAT + f];
                float acc = b1;
                #pragma unroll
                for (int f = 0; f < A_FEAT; ++f) acc += af[f] * w1[f];
                const float rr = fmaxf(acc, 0.f);
                #pragma unroll
                for (int f = 0; f < A_FEAT; ++f) pf[f] += rr * af[f];
                #pragma unroll
                for (int f = 0; f < A_FEAT; ++f) a_acc += af[f] * b2v[f];
            }
            emb[r] += a_acc;
            float* pm = W + r * 512 + lane * 8;
            *reinterpret_cast<float4*>(pm)     = make_float4(pf[0], pf[1], pf[2], pf[3]);
            *reinterpret_cast<float4*>(pm + 4) = make_float4(pf[4], pf[5], pf[6], pf[7]);
            float* pt = W + 2048 + r * 128 + lane * 2;
            pt[0] = pf[8]; pt[1] = pf[9];
        }
    }
    __builtin_amdgcn_wave_barrier();

    // ---------------- w2_a contraction ----------------
    #pragma unroll 2
    for (int k = 0; k < HD; ++k) {
        const float* wrow = ha_w2 + (size_t)k * AW2 + lane;
        float w10[A_FEAT];
        #pragma unroll
        for (int f = 0; f < A_FEAT; ++f) w10[f] = wrow[f * HD];
        #pragma unroll
        for (int r = 0; r < NR; ++r) {
            const float4 p0 = *reinterpret_cast<const float4*>(W + r * 512 + k * 8);
            const float4 p1 = *reinterpret_cast<const float4*>(W + r * 512 + k * 8 + 4);
            const float2 pt = *reinterpret_cast<const float2*>(W + 2048 + r * 128 + k * 2);
            float a = emb[r];
            a += p0.x * w10[0]; a += p0.y * w10[1]; a += p0.z * w10[2]; a += p0.w * w10[3];
            a += p1.x * w10[4]; a += p1.y * w10[5]; a += p1.z * w10[6]; a += p1.w * w10[7];
            a += pt.x * w10[8]; a += pt.y * w10[9];
            emb[r] = a;
        }
    }
    __builtin_amdgcn_wave_barrier();

    // ---------------- GRU ----------------
    float hreg[NR], hv[NR];
    #pragma unroll
    for (int r = 0; r < NR; ++r) {
        const int n = n0 + r;
        const float x = fmaxf(emb[r], 0.f);
        const float h = hidden_state[(size_t)n * HD + lane];
        hreg[r] = h;
        W[lane * 8 + r * 2]     = x;
        W[lane * 8 + r * 2 + 1] = h;
    }
    __builtin_amdgcn_wave_barrier();

    {
        float gir[NR], giz[NR], gin[NR], ghr[NR], ghz[NR], ghn[NR];
        const float bir = gru_b_ih[lane], biz = gru_b_ih[HD + lane], bin = gru_b_ih[2 * HD + lane];
        const float bhr = gru_b_hh[lane], bhz = gru_b_hh[HD + lane], bhn = gru_b_hh[2 * HD + lane];
        #pragma unroll
        for (int r = 0; r < NR; ++r) {
            gir[r] = bir; giz[r] = biz; gin[r] = bin;
            ghr[r] = bhr; ghz[r] = bhz; ghn[r] = bhn;
        }
        const float* wtih = ws + WS_WTIH;
        const float* wthh = ws + WS_WTHH;
        #pragma unroll 2
        for (int k = 0; k < HD; ++k) {
            const float wi0 = wtih[k * 192 + lane];
            const float wi1 = wtih[k * 192 + HD + lane];
            const float wi2 = wtih[k * 192 + 2 * HD + lane];
            const float wh0 = wthh[k * 192 + lane];
            const float wh1 = wthh[k * 192 + HD + lane];
            const float wh2 = wthh[k * 192 + 2 * HD + lane];
            #pragma unroll
            for (int r = 0; r < NR; ++r) {
                const float2 xh = *reinterpret_cast<const float2*>(W + k * 8 + r * 2);
                gir[r] += xh.x * wi0; giz[r] += xh.x * wi1; gin[r] += xh.x * wi2;
                ghr[r] += xh.y * wh0; ghz[r] += xh.y * wh1; ghn[r] += xh.y * wh2;
            }
        }
        #pragma unroll
        for (int r = 0; r < NR; ++r) {
            const int n = n0 + r;
            const float rg = sigm(gir[r] + ghr[r]);
            const float zg = sigm(giz[r] + ghz[r]);
            const float ng = tanhf(gin[r] + rg * ghn[r]);
            const float h = (1.f - zg) * ng + zg * hreg[r];
            hv[r] = h;
            out_hh[(size_t)n * HD + lane] = h;
            W[512 + lane * 4 + r] = h;
        }
    }
    __builtin_amdgcn_wave_barrier();

    // ---------------- q_normal ----------------
    {
        float w6[6];
        #pragma unroll
        for (int j = 0; j < 6; ++j) w6[j] = fc2_w[lane * 6 + j];
        #pragma unroll
        for (int r = 0; r < NR; ++r) {
            const int n = n0 + r;
            float pj[6];
            #pragma unroll
            for (int j = 0; j < 6; ++j) pj[j] = hv[r] * w6[j];
            #pragma unroll
            for (int o = 1; o < 64; o <<= 1) {
                #pragma unroll
                for (int j = 0; j < 6; ++j) pj[j] += __shfl_xor(pj[j], o);
            }
            if (lane < 6) {
                const float q = (lane == 0) ? pj[0] : (lane == 1) ? pj[1] : (lane == 2) ? pj[2]
                              : (lane == 3) ? pj[3] : (lane == 4) ? pj[4] : pj[5];
                out_q[(size_t)n * N_ACT + lane] = q + fc2_b[lane];
            }
        }
    }

    // ---------------- attack head (r_e recomputed from feats — no long live range) ----------------
    {
        const float* AT = ws + WS_AT;
        const float* ubp = ws + WS_UB;
        float u[NR];
        const float ubv = ubp[lane];
        #pragma unroll
        for (int r = 0; r < NR; ++r) u[r] = ubv;
        #pragma unroll 4
        for (int h = 0; h < HD; ++h) {
            const float at = AT[h * HD + lane];
            const float4 h4 = *reinterpret_cast<const float4*>(W + 512 + h * 4);
            u[0] += h4.x * at; u[1] += h4.y * at; u[2] += h4.z * at; u[3] += h4.w * at;
        }
        float w1[E_FEAT];
        #pragma unroll
        for (int f = 0; f < E_FEAT; ++f) w1[f] = he_w1[f * HD + lane];
        const float b1 = he_b1[lane];
        const float b2a = he_b2[E_FEAT * HD + lane];
        const float b2last = he_b2[E_FEAT * HD + HD];
        #pragma unroll
        for (int r = 0; r < NR; ++r) {
            const int n = n0 + r;
            const float c = wave_sum(hv[r] * b2a) + b2last;
            const float* efb = enemy_feats + (size_t)n * (N_EN * E_FEAT);
            for (int e = 0; e < N_EN; ++e) {
                float acc = b1;
                #pragma unroll
                for (int f = 0; f < E_FEAT; ++f) acc += efb[e * E_FEAT + f] * w1[f];
                const float rr = fmaxf(acc, 0.f);
                const float p = wave_sum(rr * u[r]);
                if (lane == e) out_q[(size_t)n * N_ACT + 6 + e] = p + c;
            }
        }
    }
}

extern "C" void kernel_launch(void* const* d_in, const int* in_sizes, int n_in,
                              void* d_out, int out_size, void* d_ws, size_t ws_size,
                              hipStream_t stream) {
    const float* own_feats    = (const float*)d_in[0];
    const float* enemy_feats  = (const float*)d_in[1];
    const float* ally_feats   = (const float*)d_in[2];
    const float* hidden_state = (const float*)d_in[3];
    const int*  agent_idx     = (const int*)d_in[4];
    const int*  last_act      = (const int*)d_in[5];
    const float* fc1_own_w = (const float*)d_in[7];
    const float* fc1_own_b = (const float*)d_in[8];
    const float* agent_id_emb  = (const float*)d_in[9];
    const float* action_id_emb = (const float*)d_in[10];
    const float* he_w1 = (const float*)d_in[11];
    const float* he_b1 = (const float*)d_in[12];
    const float* he_w2 = (const float*)d_in[13];
    const float* he_b2 = (const float*)d_in[14];
    const float* ha_w1 = (const float*)d_in[15];
    const float* ha_b1 = (const float*)d_in[16];
    const float* ha_w2 = (const float*)d_in[17];
    const float* ha_b2 = (const float*)d_in[18];
    const float* gru_w_ih = (const float*)d_in[19];
    const float* gru_w_hh = (const float*)d_in[20];
    const float* gru_b_ih = (const float*)d_in[21];
    const float* gru_b_hh = (const float*)d_in[22];
    const float* fc2_w = (const float*)d_in[23];
    const float* fc2_b = (const float*)d_in[24];

    const int R = in_sizes[0] / OWN_FEAT;  // 32768
    float* ws = (float*)d_ws;
    float* out_q  = (float*)d_out;
    float* out_hh = out_q + (size_t)R * N_ACT;

    prep_kernel<<<(WS_TOTAL + 255) / 256, 256, 0, stream>>>(gru_w_ih, gru_w_hh, he_w2, ws);

    const int nblocks = R / ROWS_PER_BLOCK;
    agent_kernel<<<nblocks, NWAVE * 64, 0, stream>>>(
        own_feats, enemy_feats, ally_feats, hidden_state, agent_idx, last_act,
        fc1_own_w, fc1_own_b, agent_id_emb, action_id_emb,
        he_w1, he_b1, he_w2, he_b2, ha_w1, ha_b1, ha_w2, ha_b2,
        gru_b_ih, gru_b_hh, fc2_w, fc2_b, ws,
        out_q, out_hh);
}

// Round 5
// 128.396 us; speedup vs baseline: 11.7059x; 2.2004x over previous
//
#include <hip/hip_runtime.h>
#include <hip/hip_bf16.h>

typedef short short8 __attribute__((ext_vector_type(8)));
typedef float f32x4 __attribute__((ext_vector_type(4)));

#define HD 64
#define N_EN 8
#define N_AL 7
#define E_FEAT 9
#define A_FEAT 10
#define OWN_FEAT 16
#define N_ACT 14
#define EW2 641
#define AW2 640

// GEMM K sizes (padded to multiples of 32)
#define KE 640   // enemy: 576 P | 9 sef | 16 own | 1 const | 8 aid | 14 act | 16 pad
#define KA 672   // ally : 640 P | 10 sef | 22 pad
#define KG 160   // gru  : 64 x | 64 h | 1 const | 31 pad
#define KU 96    // u    : 64 hh | 1 const | 31 pad
#define KSE 20
#define KSA 21
#define KSG 5
#define KSU 3

// B-fragment tables in ws (ushort units)
#define BE_OFF 0
#define BE_CNT (KSE*4*64*8)
#define BA_OFF (BE_OFF+BE_CNT)
#define BA_CNT (KSA*4*64*8)
#define BG_OFF (BA_OFF+BA_CNT)
#define BG_CNT (KSG*16*64*8)
#define BU_OFF (BG_OFF+BG_CNT)
#define BU_CNT (KSU*5*64*8)
#define WS_SHORTS (BU_OFF+BU_CNT)   // 132608 shorts = 265216 B

// LDS layout (bytes). Regions reuse the P area across phases.
#define P_STRIDE 676          // ushorts/row (>= KA, mult of 4)
#define LDS_AG 0              // A_gru [16] rows, stride 328 B (164 us)
#define LDS_GATES 8192        // gates [16] rows, stride 520 B
#define LDS_AU 17024          // A_u [16] rows, stride 200 B
#define LDS_U 0               // u_lds [16][66] f32
#define LDS_BYTES 21632

__device__ __forceinline__ ushort f2u(float x) {
    __hip_bfloat16 b = __float2bfloat16(x);
    ushort u; __builtin_memcpy(&u, &b, 2); return u;
}
__device__ __forceinline__ float u2f(uint u) {
    union { uint x; float f; } c; c.x = u << 16; return c.f;
}
__device__ __forceinline__ uint pk2(float a, float b) {
    return (uint)f2u(a) | ((uint)f2u(b) << 16);
}
__device__ __forceinline__ float sigm(float x) { return 1.f / (1.f + __expf(-x)); }
__device__ __forceinline__ float wave_sum(float v) {
    #pragma unroll
    for (int o = 1; o < 64; o <<= 1) v += __shfl_xor(v, o);
    return v;
}
// A-fragment: two ds_read_b64 at k-slot base; elems 0-3 = kk, 4-7 = kk+16
__device__ __forceinline__ short8 lda(const char* base, int row, int strideB, int s, int g) {
    const char* p = base + row * strideB + s * 64 + g * 8;
    union { short8 v; uint2 q[2]; } u;
    u.q[0] = *(const uint2*)p;
    u.q[1] = *(const uint2*)(p + 32);
    return u.v;
}

// ---------------- prep: build B-fragment tables ----------------
__global__ __launch_bounds__(256) void prep_kernel(
    const float* __restrict__ he_w2, const float* __restrict__ he_b2,
    const float* __restrict__ ha_w2, const float* __restrict__ ha_b2,
    const float* __restrict__ fc1_own_w, const float* __restrict__ fc1_own_b,
    const float* __restrict__ agent_id_emb, const float* __restrict__ action_id_emb,
    const float* __restrict__ gru_w_ih, const float* __restrict__ gru_w_hh,
    const float* __restrict__ gru_b_ih, const float* __restrict__ gru_b_hh,
    const float* __restrict__ fc2_w, const float* __restrict__ fc2_b,
    ushort* __restrict__ ws)
{
    const int GE = KSE * 4, GA = KSA * 4, GG = KSG * 16, GU = KSU * 5;
    const int total = (GE + GA + GG + GU) * 64;
    int idx = blockIdx.x * 256 + threadIdx.x;
    if (idx >= total) return;
    int grp = idx >> 6, lane = idx & 63;
    int g = lane >> 4, col16 = lane & 15;
    int table, s, t, slot;
    if (grp < GE)           { table = 0; int q = grp;            s = q / 4;  t = q % 4;  slot = q * 64 + lane; }
    else if (grp < GE + GA) { table = 1; int q = grp - GE;       s = q / 4;  t = q % 4;  slot = q * 64 + lane; }
    else if (grp < GE + GA + GG) { table = 2; int q = grp - GE - GA; s = q / 16; t = q % 16; slot = q * 64 + lane; }
    else                    { table = 3; int q = grp - GE - GA - GG; s = q / 5; t = q % 5; slot = q * 64 + lane; }
    const int j = t * 16 + col16;
    ushort out[8];
    #pragma unroll
    for (int e = 0; e < 8; ++e) {
        int kk = 32 * s + 4 * g + (e & 3) + 16 * (e >> 2);
        float v = 0.f;
        if (table == 0) {
            if (kk < 576)      { int f = kk >> 6, k = kk & 63; v = he_w2[k * EW2 + f * HD + j]; }
            else if (kk < 585) { int f = kk - 576; v = he_b2[f * HD + j]; }
            else if (kk < 601) { int f = kk - 585; v = fc1_own_w[f * HD + j]; }
            else if (kk == 601){ v = fc1_own_b[j]; }
            else if (kk < 610) { int a = kk - 602; v = agent_id_emb[a * HD + j]; }
            else if (kk < 624) { int a = kk - 610; v = action_id_emb[a * HD + j]; }
        } else if (table == 1) {
            if (kk < 640)      { int f = kk >> 6, k = kk & 63; v = ha_w2[k * AW2 + f * HD + j]; }
            else if (kk < 650) { int f = kk - 640; v = ha_b2[f * HD + j]; }
        } else if (table == 2) {
            int gb = j >> 6, c = j & 63;
            if (gb <= 1) {                 // merged r / z gates
                int jj = gb * 64 + c;
                if (kk < 64)        v = gru_w_ih[jj * HD + kk];
                else if (kk < 128)  v = gru_w_hh[jj * HD + kk - 64];
                else if (kk == 128) v = gru_b_ih[jj] + gru_b_hh[jj];
            } else if (gb == 2) {          // i_n
                int jj = 128 + c;
                if (kk < 64)        v = gru_w_ih[jj * HD + kk];
                else if (kk == 128) v = gru_b_ih[jj];
            } else {                       // h_n
                int jj = 128 + c;
                if (kk >= 64 && kk < 128) v = gru_w_hh[jj * HD + kk - 64];
                else if (kk == 128)       v = gru_b_hh[jj];
            }
        } else {
            if (j < 64) {
                if (kk < 64)       v = he_w2[j * EW2 + 576 + kk];
                else if (kk == 64) v = he_w2[j * EW2 + 640];
            } else if (j < 70) {
                int o = j - 64;
                if (kk < 64)       v = fc2_w[kk * 6 + o];
                else if (kk == 64) v = fc2_b[o];
            } else if (j == 70) {
                if (kk < 64)       v = he_b2[576 + kk];
                else if (kk == 64) v = he_b2[640];
            }
        }
        out[e] = f2u(v);
    }
    ushort* dst = ws + ((table == 0) ? BE_OFF : (table == 1) ? BA_OFF : (table == 2) ? BG_OFF : BU_OFF);
    *(short8*)(dst + slot * 8) = *(short8*)out;
}

// ---------------- main ----------------
__global__ __launch_bounds__(256, 4) void agent_kernel(
    const float* __restrict__ own_feats,
    const float* __restrict__ enemy_feats,
    const float* __restrict__ ally_feats,
    const float* __restrict__ hidden_state,
    const int*  __restrict__ agent_idx,
    const int*  __restrict__ last_act_idx,
    const float* __restrict__ he_w1, const float* __restrict__ he_b1,
    const float* __restrict__ ha_w1, const float* __restrict__ ha_b1,
    const ushort* __restrict__ ws,
    float* __restrict__ out_q, float* __restrict__ out_hh)
{
    __shared__ __align__(16) char smem[LDS_BYTES];
    const int tid  = threadIdx.x;
    const int lane = tid & 63;
    const int wv   = tid >> 6;
    const int n0   = blockIdx.x * 16;
    const int arow = lane & 15;     // A row / B col / D col
    const int g    = lane >> 4;     // k-slot group; D rows 4g..4g+3
    ushort* P = (ushort*)smem;

    // ===== Phase 1: enemy P-build (wave-private rows 4wv..4wv+3) =====
    {
        float w1[E_FEAT];
        #pragma unroll
        for (int f = 0; f < E_FEAT; ++f) w1[f] = he_w1[f * HD + lane];
        const float b1 = he_b1[lane];
        #pragma unroll
        for (int rr = 0; rr < 4; ++rr) {
            const int row = wv * 4 + rr, n = n0 + row;
            const float* efb = enemy_feats + (size_t)n * (N_EN * E_FEAT);
            float pf[E_FEAT], sf[E_FEAT];
            #pragma unroll
            for (int f = 0; f < E_FEAT; ++f) { pf[f] = 0.f; sf[f] = 0.f; }
            #pragma unroll
            for (int e = 0; e < N_EN; ++e) {
                float ef[E_FEAT];
                #pragma unroll
                for (int f = 0; f < E_FEAT; ++f) ef[f] = efb[e * E_FEAT + f];
                float acc = b1;
                #pragma unroll
                for (int f = 0; f < E_FEAT; ++f) acc += ef[f] * w1[f];
                const float r = fmaxf(acc, 0.f);
                #pragma unroll
                for (int f = 0; f < E_FEAT; ++f) { pf[f] += r * ef[f]; sf[f] += ef[f]; }
            }
            ushort* Pr = P + row * P_STRIDE;
            #pragma unroll
            for (int f = 0; f < E_FEAT; ++f) Pr[f * HD + lane] = f2u(pf[f]);
            if (lane == 0) {
                #pragma unroll
                for (int f = 0; f < E_FEAT; ++f) Pr[576 + f] = f2u(sf[f]);
                Pr[601] = 0x3F80;
            }
            if (lane < OWN_FEAT) Pr[585 + lane] = f2u(own_feats[(size_t)n * OWN_FEAT + lane]);
            const int ai = agent_idx[n], la = last_act_idx[n];
            if (lane < 8)      Pr[602 + lane] = (lane == ai) ? 0x3F80 : 0;
            if (lane < N_ACT)  Pr[610 + lane] = (lane == la) ? 0x3F80 : 0;
            if (lane < 16)     Pr[624 + lane] = 0;
        }
    }
    __syncthreads();

    // ===== Phase 2: enemy GEMM (acc shared with ally) =====
    f32x4 accE = {0.f, 0.f, 0.f, 0.f};
    for (int s = 0; s < KSE; ++s) {
        short8 a = lda(smem, arow, P_STRIDE * 2, s, g);
        short8 b = *(const short8*)(ws + BE_OFF + ((size_t)(s * 4 + wv) * 64 + lane) * 8);
        accE = __builtin_amdgcn_mfma_f32_16x16x32_bf16(a, b, accE, 0, 0, 0);
    }
    __syncthreads();

    // ===== Phase 3: ally P-build =====
    {
        float w1[A_FEAT];
        #pragma unroll
        for (int f = 0; f < A_FEAT; ++f) w1[f] = ha_w1[f * HD + lane];
        const float b1 = ha_b1[lane];
        #pragma unroll
        for (int rr = 0; rr < 4; ++rr) {
            const int row = wv * 4 + rr, n = n0 + row;
            const float* afb = ally_feats + (size_t)n * (N_AL * A_FEAT);
            float pf[A_FEAT], sf[A_FEAT];
            #pragma unroll
            for (int f = 0; f < A_FEAT; ++f) { pf[f] = 0.f; sf[f] = 0.f; }
            #pragma unroll
            for (int e = 0; e < N_AL; ++e) {
                float af[A_FEAT];
                #pragma unroll
                for (int f = 0; f < A_FEAT; ++f) af[f] = afb[e * A_FEAT + f];
                float acc = b1;
                #pragma unroll
                for (int f = 0; f < A_FEAT; ++f) acc += af[f] * w1[f];
                const float r = fmaxf(acc, 0.f);
                #pragma unroll
                for (int f = 0; f < A_FEAT; ++f) { pf[f] += r * af[f]; sf[f] += af[f]; }
            }
            ushort* Pr = P + row * P_STRIDE;
            #pragma unroll
            for (int f = 0; f < A_FEAT; ++f) Pr[f * HD + lane] = f2u(pf[f]);
            if (lane == 0) {
                #pragma unroll
                for (int f = 0; f < A_FEAT; ++f) Pr[640 + f] = f2u(sf[f]);
            }
            if (lane < 22) Pr[650 + lane] = 0;
        }
    }
    __syncthreads();

    // ===== Phase 4: ally GEMM (accumulate into accE) =====
    for (int s = 0; s < KSA; ++s) {
        short8 a = lda(smem, arow, P_STRIDE * 2, s, g);
        short8 b = *(const short8*)(ws + BA_OFF + ((size_t)(s * 4 + wv) * 64 + lane) * 8);
        accE = __builtin_amdgcn_mfma_f32_16x16x32_bf16(a, b, accE, 0, 0, 0);
    }
    __syncthreads();

    // ===== Phase 5: stage A_gru = [x | h | 1 | 0] =====
    #pragma unroll
    for (int j = 0; j < 4; ++j) {
        const int m = g * 4 + j;
        const float x = fmaxf(accE[j], 0.f);
        *(ushort*)(smem + LDS_AG + m * 328 + (wv * 16 + arow) * 2) = f2u(x);
    }
    {
        const int row = tid >> 4, c4 = (tid & 15) * 4;
        float4 h4 = *(const float4*)(hidden_state + (size_t)(n0 + row) * HD + c4);
        char* p = smem + LDS_AG + row * 328 + (64 + c4) * 2;
        *(uint*)p       = pk2(h4.x, h4.y);
        *(uint*)(p + 4) = pk2(h4.z, h4.w);
        if (tid < 16) *(ushort*)(smem + LDS_AG + tid * 328 + 128 * 2) = 0x3F80;
        for (int i = tid; i < 16 * 31; i += 256) {
            int r2 = i / 31, c = 129 + i % 31;
            *(ushort*)(smem + LDS_AG + r2 * 328 + c * 2) = 0;
        }
    }
    __syncthreads();

    // ===== Phase 6: GRU GEMM (N=256: r|z|i_n|h_n), wave wv owns j in [64wv,64wv+64) =====
    {
        f32x4 accG[4] = {{0.f,0.f,0.f,0.f},{0.f,0.f,0.f,0.f},{0.f,0.f,0.f,0.f},{0.f,0.f,0.f,0.f}};
        for (int s = 0; s < KSG; ++s) {
            short8 a = lda(smem + LDS_AG, arow, 328, s, g);
            #pragma unroll
            for (int tt = 0; tt < 4; ++tt) {
                const int t = wv * 4 + tt;
                short8 b = *(const short8*)(ws + BG_OFF + ((size_t)(s * 16 + t) * 64 + lane) * 8);
                accG[tt] = __builtin_amdgcn_mfma_f32_16x16x32_bf16(a, b, accG[tt], 0, 0, 0);
            }
        }
        #pragma unroll
        for (int tt = 0; tt < 4; ++tt)
            #pragma unroll
            for (int j = 0; j < 4; ++j) {
                const int m = g * 4 + j, jc = (wv * 4 + tt) * 16 + arow;
                *(ushort*)(smem + LDS_GATES + m * 520 + jc * 2) = f2u(accG[tt][j]);
            }
    }
    __syncthreads();

    // ===== Phase 7: pointwise GRU + stage A_u =====
    {
        const int row = tid >> 4, c4 = (tid & 15) * 4;
        const char* gb = smem + LDS_GATES + row * 520;
        uint2 rv = *(const uint2*)(gb + c4 * 2);
        uint2 zv = *(const uint2*)(gb + 128 + c4 * 2);
        uint2 iv = *(const uint2*)(gb + 256 + c4 * 2);
        uint2 nv = *(const uint2*)(gb + 384 + c4 * 2);
        float4 h4 = *(const float4*)(hidden_state + (size_t)(n0 + row) * HD + c4);
        float hr[4] = {u2f(rv.x & 0xffffu), u2f(rv.x >> 16), u2f(rv.y & 0xffffu), u2f(rv.y >> 16)};
        float hz[4] = {u2f(zv.x & 0xffffu), u2f(zv.x >> 16), u2f(zv.y & 0xffffu), u2f(zv.y >> 16)};
        float hi[4] = {u2f(iv.x & 0xffffu), u2f(iv.x >> 16), u2f(iv.y & 0xffffu), u2f(iv.y >> 16)};
        float hn[4] = {u2f(nv.x & 0xffffu), u2f(nv.x >> 16), u2f(nv.y & 0xffffu), u2f(nv.y >> 16)};
        float hcur[4] = {h4.x, h4.y, h4.z, h4.w};
        float hh[4];
        #pragma unroll
        for (int cc = 0; cc < 4; ++cc) {
            const float r = sigm(hr[cc]);
            const float z = sigm(hz[cc]);
            const float nng = tanhf(hi[cc] + r * hn[cc]);
            hh[cc] = (1.f - z) * nng + z * hcur[cc];
        }
        float4 o4 = make_float4(hh[0], hh[1], hh[2], hh[3]);
        *(float4*)(out_hh + (size_t)(n0 + row) * HD + c4) = o4;
        char* p = smem + LDS_AU + row * 200 + c4 * 2;
        *(uint*)p       = pk2(hh[0], hh[1]);
        *(uint*)(p + 4) = pk2(hh[2], hh[3]);
        if (tid < 16) *(ushort*)(smem + LDS_AU + tid * 200 + 64 * 2) = 0x3F80;
        for (int i = tid; i < 16 * 31; i += 256) {
            int r2 = i / 31, c = 65 + i % 31;
            *(ushort*)(smem + LDS_AU + r2 * 200 + c * 2) = 0;
        }
    }
    __syncthreads();

    // ===== Phase 8: u-GEMM (N=80: u[64] | fc2 q[6] | c | pad) =====
    {
        f32x4 accU = {0.f, 0.f, 0.f, 0.f};
        f32x4 accQ = {0.f, 0.f, 0.f, 0.f};
        for (int s = 0; s < KSU; ++s) {
            short8 a = lda(smem + LDS_AU, arow, 200, s, g);
            short8 b = *(const short8*)(ws + BU_OFF + ((size_t)(s * 5 + wv) * 64 + lane) * 8);
            accU = __builtin_amdgcn_mfma_f32_16x16x32_bf16(a, b, accU, 0, 0, 0);
            if (wv == 0) {
                short8 b2 = *(const short8*)(ws + BU_OFF + ((size_t)(s * 5 + 4) * 64 + lane) * 8);
                accQ = __builtin_amdgcn_mfma_f32_16x16x32_bf16(a, b2, accQ, 0, 0, 0);
            }
        }
        float* uld = (float*)(smem + LDS_U);
        #pragma unroll
        for (int j = 0; j < 4; ++j) {
            const int m = g * 4 + j;
            uld[m * 66 + wv * 16 + arow] = accU[j];
        }
        if (wv == 0) {
            #pragma unroll
            for (int j = 0; j < 4; ++j) {
                const int m = g * 4 + j;
                if (arow < 6)       out_q[(size_t)(n0 + m) * N_ACT + arow] = accQ[j];
                else if (arow == 6) uld[m * 66 + 64] = accQ[j];
            }
        }
    }
    __syncthreads();

    // ===== Phase 9: attack head =====
    {
        float w1[E_FEAT];
        #pragma unroll
        for (int f = 0; f < E_FEAT; ++f) w1[f] = he_w1[f * HD + lane];
        const float b1 = he_b1[lane];
        const float* uld = (const float*)(smem + LDS_U);
        #pragma unroll
        for (int rr = 0; rr < 4; ++rr) {
            const int row = wv * 4 + rr, n = n0 + row;
            const float uk = uld[row * 66 + lane];
            const float ct = uld[row * 66 + 64];
            const float* efb = enemy_feats + (size_t)n * (N_EN * E_FEAT);
            #pragma unroll
            for (int e = 0; e < N_EN; ++e) {
                float acc = b1;
                #pragma unroll
                for (int f = 0; f < E_FEAT; ++f) acc += efb[e * E_FEAT + f] * w1[f];
                float p = fmaxf(acc, 0.f) * uk;
                p = wave_sum(p);
                if (lane == e) out_q[(size_t)n * N_ACT + 6 + e] = p + ct;
            }
        }
    }
}

extern "C" void kernel_launch(void* const* d_in, const int* in_sizes, int n_in,
                              void* d_out, int out_size, void* d_ws, size_t ws_size,
                              hipStream_t stream) {
    const float* own_feats    = (const float*)d_in[0];
    const float* enemy_feats  = (const float*)d_in[1];
    const float* ally_feats   = (const float*)d_in[2];
    const float* hidden_state = (const float*)d_in[3];
    const int*  agent_idx     = (const int*)d_in[4];
    const int*  last_act      = (const int*)d_in[5];
    const float* fc1_own_w = (const float*)d_in[7];
    const float* fc1_own_b = (const float*)d_in[8];
    const float* agent_id_emb  = (const float*)d_in[9];
    const float* action_id_emb = (const float*)d_in[10];
    const float* he_w1 = (const float*)d_in[11];
    const float* he_b1 = (const float*)d_in[12];
    const float* he_w2 = (const float*)d_in[13];
    const float* he_b2 = (const float*)d_in[14];
    const float* ha_w1 = (const float*)d_in[15];
    const float* ha_b1 = (const float*)d_in[16];
    const float* ha_w2 = (const float*)d_in[17];
    const float* ha_b2 = (const float*)d_in[18];
    const float* gru_w_ih = (const float*)d_in[19];
    const float* gru_w_hh = (const float*)d_in[20];
    const float* gru_b_ih = (const float*)d_in[21];
    const float* gru_b_hh = (const float*)d_in[22];
    const float* fc2_w = (const float*)d_in[23];
    const float* fc2_b = (const float*)d_in[24];

    const int R = in_sizes[0] / OWN_FEAT;  // 32768
    ushort* ws = (ushort*)d_ws;
    float* out_q  = (float*)d_out;
    float* out_hh = out_q + (size_t)R * N_ACT;

    prep_kernel<<<65, 256, 0, stream>>>(
        he_w2, he_b2, ha_w2, ha_b2, fc1_own_w, fc1_own_b,
        agent_id_emb, action_id_emb, gru_w_ih, gru_w_hh, gru_b_ih, gru_b_hh,
        fc2_w, fc2_b, ws);

    agent_kernel<<<R / 16, 256, 0, stream>>>(
        own_feats, enemy_feats, ally_feats, hidden_state, agent_idx, last_act,
        he_w1, he_b1, ha_w1, ha_b1, ws, out_q, out_hh);
}